// Round 9
// baseline (312.351 us; speedup 1.0000x reference)
//
#include <hip/hip_runtime.h>

#define IN_F 32
#define HID 64
#define OUTF 16
#define NSUB 8                     // sub-buckets per dst (XCD-locality heuristic)
#define SB_CAP 16                  // records per sub-bucket
#define OVF_CAP 65536
#define ORD_NEG_INF 0x007FFFFFu    // ordenc(-inf), "empty" marker

typedef _Float16 v8h __attribute__((ext_vector_type(8)));
typedef float v4f __attribute__((ext_vector_type(4)));
typedef float v2f __attribute__((ext_vector_type(2)));

__device__ __forceinline__ unsigned ordenc(float v) {
  unsigned b = __float_as_uint(v);
  return (b & 0x80000000u) ? ~b : (b | 0x80000000u);
}
__device__ __forceinline__ float orddec(unsigned u) {
  unsigned b = (u & 0x80000000u) ? (u & 0x7FFFFFFFu) : ~u;
  return __uint_as_float(b);
}
__device__ __forceinline__ unsigned short f2h_bits(float f) {
  _Float16 h = (_Float16)f; unsigned short u; __builtin_memcpy(&u, &h, 2); return u;
}
__device__ __forceinline__ float h_bits2f(unsigned short u) {
  _Float16 h; __builtin_memcpy(&h, &u, 2); return (float)h;
}

// Fused: scatter (blocks [0, nSB)) + node_pre (blocks [nSB, nSB+512)).
// R0-verified config: 4 edges/thread, SB_CAP=16 (overflow ~= 0).
// Q back to f32 (R9: bucket build consumes f32 pairs; removes Q fp16 rounding).
__global__ __launch_bounds__(256) void pre_scatter_kernel(
    const float* __restrict__ x, const int* __restrict__ ei,
    const float* __restrict__ ea, const float* __restrict__ W1,
    const float* __restrict__ b1,
    float* __restrict__ P, float* __restrict__ Q,
    uint2* __restrict__ rec, int* __restrict__ cnt,
    int* __restrict__ ovf, int* __restrict__ ovf_cnt,
    int E, int N, int nSB)
{
  if (blockIdx.x < (unsigned)nSB) {
    // ---------------- scatter ----------------
    const int t = threadIdx.x;
    const int base = blockIdx.x * 1024;
    const int g = blockIdx.x & (NSUB - 1);   // ~XCD id (perf heuristic only)
    int e[4], s[4], d[4], pos[4];
    bool v[4];
#pragma unroll
    for (int i = 0; i < 4; ++i) {
      e[i] = base + i * 256 + t;
      v[i] = e[i] < E;
      int ec = v[i] ? e[i] : 0;
      s[i] = ei[ec];
      d[i] = ei[(size_t)E + ec];
    }
#pragma unroll
    for (int i = 0; i < 4; ++i)
      pos[i] = v[i] ? atomicAdd(&cnt[d[i] * NSUB + g], 1) : SB_CAP;
    float a0[4], a1[4], a2[4];
#pragma unroll
    for (int i = 0; i < 4; ++i) {
      int ec = v[i] ? e[i] : 0;
      a0[i] = ea[ec * 3 + 0]; a1[i] = ea[ec * 3 + 1]; a2[i] = ea[ec * 3 + 2];
    }
#pragma unroll
    for (int i = 0; i < 4; ++i) {
      if (!v[i]) continue;
      if (pos[i] < SB_CAP) {
        uint2 r;
        r.x = (unsigned)s[i] | ((unsigned)f2h_bits(a0[i]) << 16);  // src < 65536
        r.y = (unsigned)f2h_bits(a1[i]) | ((unsigned)f2h_bits(a2[i]) << 16);
        rec[((size_t)d[i] * NSUB + g) * SB_CAP + pos[i]] = r;
      } else {
        int oi = atomicAdd(ovf_cnt, 1);
        if (oi < OVF_CAP) ovf[oi] = e[i];
      }
    }
    return;
  }
  // ---------------- node_pre ----------------
  const int lane = threadIdx.x & 63;
  float w1d[IN_F], w1b[IN_F];
#pragma unroll
  for (int c = 0; c < IN_F; ++c) {
    w1b[c] = W1[(IN_F + c) * HID + lane];
    w1d[c] = W1[c * HID + lane] - w1b[c];
  }
  const float b1v = b1[lane];
  int gw = __builtin_amdgcn_readfirstlane((((int)blockIdx.x - nSB) << 2) | (threadIdx.x >> 6));
  const int nwaves = 512 << 2;
  for (int n = gw; n < N; n += nwaves) {
    float p = b1v, q = 0.f;
#pragma unroll
    for (int c = 0; c < IN_F; ++c) {
      float xv = x[n * IN_F + c];
      p = fmaf(xv, w1d[c], p);
      q = fmaf(xv, w1b[c], q);
    }
    P[n * HID + lane] = p;
    Q[n * HID + lane] = q;
  }
}

// One wave per dst, 16x16x32 MFMA (R8 structure). R9 change: the hB BUILD is
// parallelized across lanes as (edge-octet x channel-group): lane = el0*8+cg
// computes edges {el0, el0+8} x channels [cg*8, cg*8+8) with float2 (pk) math.
// Replaces the edge-serial build (32 readlane + 48 cvt + 16 ds_write_b16 +
// 16 scalar Q loads per tile) with 4 shfl + 6 cvt + 2 ds_write_b128 + 4
// dwordx4 Q loads per tile. Accumulation stays f32 (numerics == R8 or better).
__global__ __launch_bounds__(256) void bucket_kernel(
    const uint2* __restrict__ rec, const int* __restrict__ cnt,
    const float* __restrict__ W1, const float* __restrict__ W2,
    const float* __restrict__ P, const float* __restrict__ Q,
    unsigned* __restrict__ agg, int N)
{
  __shared__ __align__(16) _Float16 hB[4][16][72];     // [wave][edge][ch]

  const int wave = threadIdx.x >> 6;
  const int lane = threadIdx.x & 63;
  const int quad = lane >> 4;
  const int eidx = lane & 15;
  // channel this lane stores in the final permuted row write
  const int mych = ((eidx >> 2) << 4) + (quad << 2) + (eidx & 3);
  // build mapping: this lane builds edges {el0, el0+8} x channels [cg*8, cg*8+8)
  const int cg  = lane & 7;
  const int el0 = lane >> 3;

  // A-operand: W2^T fragments, fp16, loop-invariant (R2-verified).
  v8h a_frag[4][2];
#pragma unroll
  for (int t = 0; t < 4; ++t)
#pragma unroll
    for (int ks = 0; ks < 2; ++ks)
#pragma unroll
      for (int j = 0; j < 8; ++j)
        a_frag[t][ks][j] = (_Float16)W2[(ks * 32 + quad * 8 + j) * HID + t * 16 + eidx];

  // W1 attr rows for this lane's 8 channels, f32 pairs
  v2f w0v[4], w1v[4], w2v[4];
#pragma unroll
  for (int k = 0; k < 4; ++k) {
    w0v[k] = *(const v2f*)&W1[(2 * IN_F + 0) * HID + cg * 8 + 2 * k];
    w1v[k] = *(const v2f*)&W1[(2 * IN_F + 1) * HID + cg * 8 + 2 * k];
    w2v[k] = *(const v2f*)&W1[(2 * IN_F + 2) * HID + cg * 8 + 2 * k];
  }

  const int gwave = __builtin_amdgcn_readfirstlane((blockIdx.x << 2) | wave);
  const int nw = gridDim.x << 2;

  int d = gwave;
  if (d >= N) return;   // waves are independent (no cross-wave LDS / syncthreads)

  // prefetch for dst dd: counts -> prefix -> record regs (lane i holds record i)
  // + P row chunk (this lane's 8 channels). Round 2 only when m > 64 (rare).
  int m; uint2 r0, r1; v2f pvN[4];
  auto prefetch = [&](int dd) {
    const uint4 ca = *(const uint4*)&cnt[(size_t)dd * NSUB];
    const uint4 cb = *(const uint4*)&cnt[(size_t)dd * NSUB + 4];
    int c0 = min((int)ca.x, SB_CAP), c1 = min((int)ca.y, SB_CAP);
    int c2 = min((int)ca.z, SB_CAP), c3 = min((int)ca.w, SB_CAP);
    int c4 = min((int)cb.x, SB_CAP), c5 = min((int)cb.y, SB_CAP);
    int c6 = min((int)cb.z, SB_CAP), c7 = min((int)cb.w, SB_CAP);
    int p1 = c0, p2 = p1 + c1, p3 = p2 + c2, p4 = p3 + c3;
    int p5 = p4 + c4, p6 = p5 + c5, p7 = p6 + c6;
    m = p7 + c7;
    {
      const int i = lane;
      if (i < m) {
        int g = 0, base = 0;
        if (i >= p1) { g = 1; base = p1; }
        if (i >= p2) { g = 2; base = p2; }
        if (i >= p3) { g = 3; base = p3; }
        if (i >= p4) { g = 4; base = p4; }
        if (i >= p5) { g = 5; base = p5; }
        if (i >= p6) { g = 6; base = p6; }
        if (i >= p7) { g = 7; base = p7; }
        r0 = rec[((size_t)dd * NSUB + g) * SB_CAP + (i - base)];
      }
    }
    if (m > 64) {   // wave-uniform rare branch
      const int i = 64 + lane;
      if (i < m) {
        int g = 0, base = 0;
        if (i >= p1) { g = 1; base = p1; }
        if (i >= p2) { g = 2; base = p2; }
        if (i >= p3) { g = 3; base = p3; }
        if (i >= p4) { g = 4; base = p4; }
        if (i >= p5) { g = 5; base = p5; }
        if (i >= p6) { g = 6; base = p6; }
        if (i >= p7) { g = 7; base = p7; }
        r1 = rec[((size_t)dd * NSUB + g) * SB_CAP + (i - base)];
      }
    }
#pragma unroll
    for (int k = 0; k < 4; ++k)
      pvN[k] = *(const v2f*)&P[(size_t)dd * HID + cg * 8 + 2 * k];
  };

  prefetch(d);

  while (d < N) {
    const int dn = d + nw;
    const int m_cur = m;
    uint2 ra = r0, rb = r1;   // active records for this dst
    v2f pv[4];
#pragma unroll
    for (int k = 0; k < 4; ++k) pv[k] = pvN[k];

    if (m_cur > 0) {
      // ---- pad reg records: lanes >= m_cur get a copy of the last record ----
      {
        const int lm = m_cur - 1;
        unsigned rlx, rly;
        if (lm < 64) {
          rlx = (unsigned)__builtin_amdgcn_readlane((int)ra.x, lm);
          rly = (unsigned)__builtin_amdgcn_readlane((int)ra.y, lm);
        } else {
          rlx = (unsigned)__builtin_amdgcn_readlane((int)rb.x, lm & 63);
          rly = (unsigned)__builtin_amdgcn_readlane((int)rb.y, lm & 63);
        }
        if (lane >= m_cur)      { ra.x = rlx; ra.y = rly; }
        if (lane + 64 >= m_cur) { rb.x = rlx; rb.y = rly; }
      }

      // ---- tile-0 Q prefetch: this lane's 2 edges x 8 channels (f32 pairs) ----
      v2f qA[4], qB[4];
      {
        unsigned sx0 = (unsigned)__shfl((int)ra.x, el0, 64) & 0xFFFFu;
        unsigned sx1 = (unsigned)__shfl((int)ra.x, el0 + 8, 64) & 0xFFFFu;
        const v2f* q0 = (const v2f*)&Q[(size_t)sx0 * HID + cg * 8];
        const v2f* q1 = (const v2f*)&Q[(size_t)sx1 * HID + cg * 8];
#pragma unroll
        for (int k = 0; k < 4; ++k) { qA[k] = q0[k]; qB[k] = q1[k]; }
      }

      // ---- prefetch next dst (counts -> records -> P), lands under tile work ----
      if (dn < N) prefetch(dn);

      // ---- process current dst: 16-edge MFMA tiles ----
      float maxv[4][4];
#pragma unroll
      for (int t = 0; t < 4; ++t)
#pragma unroll
        for (int r = 0; r < 4; ++r) maxv[t][r] = -INFINITY;

      const int ntile = (m_cur + 15) >> 4;
      for (int tb = 0; tb < ntile; ++tb) {
        const unsigned rsx = (tb < 4) ? ra.x : rb.x;
        const unsigned rsy = (tb < 4) ? ra.y : rb.y;
        const int b16 = (tb & 3) << 4;

        // broadcast this lane's 2 edge records (per-lane src -> ds_bpermute)
        const unsigned rx0 = (unsigned)__shfl((int)rsx, b16 + el0, 64);
        const unsigned ry0 = (unsigned)__shfl((int)rsy, b16 + el0, 64);
        const unsigned rx1 = (unsigned)__shfl((int)rsx, b16 + el0 + 8, 64);
        const unsigned ry1 = (unsigned)__shfl((int)rsy, b16 + el0 + 8, 64);
        const float a00 = h_bits2f((unsigned short)(rx0 >> 16));
        const float a01 = h_bits2f((unsigned short)(ry0 & 0xFFFFu));
        const float a02 = h_bits2f((unsigned short)(ry0 >> 16));
        const float a10 = h_bits2f((unsigned short)(rx1 >> 16));
        const float a11 = h_bits2f((unsigned short)(ry1 & 0xFFFFu));
        const float a12 = h_bits2f((unsigned short)(ry1 >> 16));

        v2f pA[4], pB[4];
#pragma unroll
        for (int k = 0; k < 4; ++k) { pA[k] = pv[k] + qA[k]; pB[k] = pv[k] + qB[k]; }
#pragma unroll
        for (int k = 0; k < 4; ++k) { pA[k] += a00 * w0v[k]; pB[k] += a10 * w0v[k]; }
#pragma unroll
        for (int k = 0; k < 4; ++k) { pA[k] += a01 * w1v[k]; pB[k] += a11 * w1v[k]; }
#pragma unroll
        for (int k = 0; k < 4; ++k) { pA[k] += a02 * w2v[k]; pB[k] += a12 * w2v[k]; }

        // next-tile Q loads (qA/qB consumed above; hides under relu+MFMA)
        if (tb + 1 < ntile) {
          const unsigned rnx = (tb + 1 < 4) ? ra.x : rb.x;
          const int bn = ((tb + 1) & 3) << 4;
          unsigned sx0 = (unsigned)__shfl((int)rnx, bn + el0, 64) & 0xFFFFu;
          unsigned sx1 = (unsigned)__shfl((int)rnx, bn + el0 + 8, 64) & 0xFFFFu;
          const v2f* q0 = (const v2f*)&Q[(size_t)sx0 * HID + cg * 8];
          const v2f* q1 = (const v2f*)&Q[(size_t)sx1 * HID + cg * 8];
#pragma unroll
          for (int k = 0; k < 4; ++k) { qA[k] = q0[k]; qB[k] = q1[k]; }
        }

        // relu + fp16 (RNE) pack + 16B LDS stores
        {
          uint4 u;
          unsigned hw[4];
#pragma unroll
          for (int k = 0; k < 4; ++k) {
            float x0 = fmaxf(pA[k].x, 0.f), x1 = fmaxf(pA[k].y, 0.f);
            hw[k] = (unsigned)f2h_bits(x0) | ((unsigned)f2h_bits(x1) << 16);
          }
          u.x = hw[0]; u.y = hw[1]; u.z = hw[2]; u.w = hw[3];
          *(uint4*)&hB[wave][el0][cg * 8] = u;
#pragma unroll
          for (int k = 0; k < 4; ++k) {
            float x0 = fmaxf(pB[k].x, 0.f), x1 = fmaxf(pB[k].y, 0.f);
            hw[k] = (unsigned)f2h_bits(x0) | ((unsigned)f2h_bits(x1) << 16);
          }
          u.x = hw[0]; u.y = hw[1]; u.z = hw[2]; u.w = hw[3];
          *(uint4*)&hB[wave][el0 + 8][cg * 8] = u;
        }
        __builtin_amdgcn_wave_barrier();

        const v8h bf0 = *(const v8h*)&hB[wave][eidx][quad * 8];
        const v8h bf1 = *(const v8h*)&hB[wave][eidx][32 + quad * 8];
#pragma unroll
        for (int t = 0; t < 4; ++t) {
          v4f acc = (v4f){0.f, 0.f, 0.f, 0.f};
          acc = __builtin_amdgcn_mfma_f32_16x16x32_f16(a_frag[t][0], bf0, acc, 0, 0, 0);
          acc = __builtin_amdgcn_mfma_f32_16x16x32_f16(a_frag[t][1], bf1, acc, 0, 0, 0);
#pragma unroll
          for (int r = 0; r < 4; ++r) maxv[t][r] = fmaxf(maxv[t][r], acc[r]);
        }
        __builtin_amdgcn_wave_barrier();
      }

      // ---- butterfly max over the 16 edge-columns, direct permuted row store ----
#pragma unroll
      for (int t = 0; t < 4; ++t)
#pragma unroll
        for (int r = 0; r < 4; ++r) {
          float v = maxv[t][r];
          v = fmaxf(v, __shfl_xor(v, 1, 64));
          v = fmaxf(v, __shfl_xor(v, 2, 64));
          v = fmaxf(v, __shfl_xor(v, 4, 64));
          v = fmaxf(v, __shfl_xor(v, 8, 64));
          maxv[t][r] = v;
        }
      float val = maxv[0][0];
#pragma unroll
      for (int t = 0; t < 4; ++t)
#pragma unroll
        for (int r = 0; r < 4; ++r)
          val = (eidx == t * 4 + r) ? maxv[t][r] : val;
      agg[(size_t)d * HID + mych] = ordenc(val);   // permutation within one 256B row
    } else {
      // empty dst; still run the next-dst prefetch to keep the pipeline primed
      if (dn < N) prefetch(dn);
      agg[(size_t)d * HID + lane] = ORD_NEG_INF;
    }
    d = dn;
  }
}

// Fallback for sub-bucket overflow (expected ~0 edges). fp32-exact path.
// atomicMax (runs after bucket_kernel's plain stores; ordenc(finite) > ORD_NEG_INF).
__global__ __launch_bounds__(256) void overflow_kernel(
    const int* __restrict__ ei, const float* __restrict__ ea,
    const float* __restrict__ W1, const float* __restrict__ W2,
    const float* __restrict__ P, const float* __restrict__ Q,
    const int* __restrict__ ovf, const int* __restrict__ ovf_cnt,
    unsigned* __restrict__ agg, int E)
{
  __shared__ float hsh[4][HID];
  const int wave = threadIdx.x >> 6;
  const int lane = threadIdx.x & 63;

  int M = *ovf_cnt;
  if (M > OVF_CAP) M = OVF_CAP;
  if (M == 0) return;

  float w2r[HID];
#pragma unroll
  for (int j = 0; j < HID; ++j) w2r[j] = W2[j * HID + lane];
  const float w1c0 = W1[(2 * IN_F + 0) * HID + lane];
  const float w1c1 = W1[(2 * IN_F + 1) * HID + lane];
  const float w1c2 = W1[(2 * IN_F + 2) * HID + lane];

  const int gwave = __builtin_amdgcn_readfirstlane((blockIdx.x << 2) | wave);
  const int nw = gridDim.x << 2;
  for (int k = gwave; k < M; k += nw) {
    int e = ovf[k];
    int s = ei[e];
    int d = ei[(size_t)E + e];
    float pre = P[(size_t)d * HID + lane] + Q[(size_t)s * HID + lane];
    pre = fmaf(ea[e * 3 + 0], w1c0, pre);
    pre = fmaf(ea[e * 3 + 1], w1c1, pre);
    pre = fmaf(ea[e * 3 + 2], w1c2, pre);
    hsh[wave][lane] = fmaxf(pre, 0.f);
    __builtin_amdgcn_wave_barrier();
    float mv = 0.f;
#pragma unroll
    for (int j = 0; j < HID; ++j) mv = fmaf(hsh[wave][j], w2r[j], mv);
    atomicMax(&agg[(size_t)d * HID + lane], ordenc(mv));
    __builtin_amdgcn_wave_barrier();
  }
}

// 16 nodes per block: decode agg (empty -> 0, else +b2), out = sigmoid(agg @ Wo + bo)
__global__ __launch_bounds__(256) void out_kernel(
    const unsigned* __restrict__ agg,
    const float* __restrict__ b2,
    const float* __restrict__ Wo, const float* __restrict__ bo,
    float* __restrict__ out, int N)
{
  __shared__ float Wos[HID * OUTF];
  __shared__ float bos[OUTF];
  __shared__ float b2s[HID];
  __shared__ float aggs[16][HID + 1];

  for (int i = threadIdx.x; i < HID * OUTF; i += 256) Wos[i] = Wo[i];
  if (threadIdx.x < OUTF) bos[threadIdx.x] = bo[threadIdx.x];
  if (threadIdx.x < HID) b2s[threadIdx.x] = b2[threadIdx.x];
  __syncthreads();

  const int nodeBase = blockIdx.x * 16;
  {
    int ln = threadIdx.x >> 4;
    int k0 = (threadIdx.x & 15) * 4;
    int n = nodeBase + ln;
    if (n < N) {
      const uint4 u = *(const uint4*)&agg[(size_t)n * HID + k0];
      aggs[ln][k0 + 0] = (u.x == ORD_NEG_INF) ? 0.f : orddec(u.x) + b2s[k0 + 0];
      aggs[ln][k0 + 1] = (u.y == ORD_NEG_INF) ? 0.f : orddec(u.y) + b2s[k0 + 1];
      aggs[ln][k0 + 2] = (u.z == ORD_NEG_INF) ? 0.f : orddec(u.z) + b2s[k0 + 2];
      aggs[ln][k0 + 3] = (u.w == ORD_NEG_INF) ? 0.f : orddec(u.w) + b2s[k0 + 3];
    }
  }
  __syncthreads();
  {
    int ln = threadIdx.x >> 4;
    int o = threadIdx.x & 15;
    int n = nodeBase + ln;
    if (n < N) {
      float acc = bos[o];
#pragma unroll
      for (int k = 0; k < HID; ++k) acc = fmaf(aggs[ln][k], Wos[k * OUTF + o], acc);
      out[n * OUTF + o] = 1.f / (1.f + __expf(-acc));
    }
  }
}

extern "C" void kernel_launch(void* const* d_in, const int* in_sizes, int n_in,
                              void* d_out, int out_size, void* d_ws, size_t ws_size,
                              hipStream_t stream) {
  const float* x  = (const float*)d_in[0];
  const int*   ei = (const int*)d_in[1];
  const float* ea = (const float*)d_in[2];
  const float* W1 = (const float*)d_in[3];
  const float* b1 = (const float*)d_in[4];
  const float* W2 = (const float*)d_in[5];
  const float* b2 = (const float*)d_in[6];
  const float* Wo = (const float*)d_in[7];
  const float* bo = (const float*)d_in[8];
  float* out = (float*)d_out;

  const int N = in_sizes[0] / IN_F;   // 50000
  const int E = in_sizes[1] / 2;      // 1600000

  // ws layout: P(12.8M) | Q f32(12.8M) | agg(12.8M) | rec N*8*16 uint2(51.2M)
  //          | cnt N*8 i32(1.6M) | ovf_cnt | ovf   -> ~91 MB total (R2-proven)
  char* w = (char*)d_ws;
  float*     Pp  = (float*)w;                    w += (size_t)N * HID * 4;
  float*     Qp  = (float*)w;                    w += (size_t)N * HID * 4;
  unsigned*  agg = (unsigned*)w;                 w += (size_t)N * HID * 4;
  uint2*     rec = (uint2*)w;                    w += (size_t)N * NSUB * SB_CAP * 8;
  int*       cnt = (int*)w;                      w += (size_t)N * NSUB * 4;
  int*   ovf_cnt = (int*)w;                      w += 16;
  int*       ovf = (int*)w;

  hipMemsetAsync(cnt, 0, (size_t)N * NSUB * 4 + 16, stream);

  const int nSB = (E + 1023) / 1024;   // scatter blocks (4 edges/thread)
  pre_scatter_kernel<<<nSB + 512, 256, 0, stream>>>(
      x, ei, ea, W1, b1, Pp, Qp, rec, cnt, ovf, ovf_cnt, E, N, nSB);
  bucket_kernel<<<4096, 256, 0, stream>>>(rec, cnt, W1, W2, Pp, Qp, agg, N);
  overflow_kernel<<<256, 256, 0, stream>>>(ei, ea, W1, W2, Pp, Qp, ovf, ovf_cnt, agg, E);
  out_kernel<<<(N + 15) / 16, 256, 0, stream>>>(agg, b2, Wo, bo, out, N);
}

// Round 10
// 264.539 us; speedup vs baseline: 1.1807x; 1.1807x over previous
//
#include <hip/hip_runtime.h>

#define IN_F 32
#define HID 64
#define OUTF 16
#define DPB 128                    // dsts per coarse bucket
#define CAPB 5120                  // coarse slots per bucket (E[b]=4096, +16 sigma)
#define RSL 80                     // rec slots per dst (Pois(32): P(m>80) ~ 1e-13)
#define OVF_CAP 65536
#define ORD_NEG_INF 0x007FFFFFu    // ordenc(-inf), "empty" marker

typedef _Float16 v8h __attribute__((ext_vector_type(8)));
typedef float v4f __attribute__((ext_vector_type(4)));

__device__ __forceinline__ unsigned ordenc(float v) {
  unsigned b = __float_as_uint(v);
  return (b & 0x80000000u) ? ~b : (b | 0x80000000u);
}
__device__ __forceinline__ float orddec(unsigned u) {
  unsigned b = (u & 0x80000000u) ? (u & 0x7FFFFFFFu) : ~u;
  return __uint_as_float(b);
}
__device__ __forceinline__ unsigned short f2h_bits(float f) {
  _Float16 h = (_Float16)f; unsigned short u; __builtin_memcpy(&u, &h, 2); return u;
}
__device__ __forceinline__ float h_bits2f(unsigned short u) {
  _Float16 h; __builtin_memcpy(&h, &u, 2); return (float)h;
}

// ---------------------------------------------------------------------------
// P0: per-block coarse histogram (LDS atomics only — R9 post-mortem: the old
// pre_scatter was bound by 1.6M device-scope atomicAdds at the IF atomic
// units, ~6/cy device-wide ~= 111us ~= measured) + node_pre fused as extra
// blocks (unchanged P/Q compute; Q fp16 as in R8).
// ---------------------------------------------------------------------------
__global__ __launch_bounds__(256) void p0_kernel(
    const int* __restrict__ ei,
    const float* __restrict__ x, const float* __restrict__ W1,
    const float* __restrict__ b1,
    float* __restrict__ P, _Float16* __restrict__ Q,
    unsigned* __restrict__ hist, int E, int N, int nSB, int NBKT)
{
  if (blockIdx.x < (unsigned)nSB) {
    __shared__ unsigned h[512];                 // NBKT <= 512 (N <= 65536)
    for (int i = threadIdx.x; i < NBKT; i += 256) h[i] = 0;
    __syncthreads();
    const int base = blockIdx.x * 1024;
    int d[4]; bool v[4];
#pragma unroll
    for (int i = 0; i < 4; ++i) {
      int e = base + i * 256 + threadIdx.x;
      v[i] = e < E;
      d[i] = ei[(size_t)E + (v[i] ? e : 0)];
    }
#pragma unroll
    for (int i = 0; i < 4; ++i)
      if (v[i]) atomicAdd(&h[d[i] >> 7], 1u);   // LDS atomic
    __syncthreads();
    for (int i = threadIdx.x; i < NBKT; i += 256)
      hist[(size_t)blockIdx.x * NBKT + i] = h[i];
    return;
  }
  // ---------------- node_pre ----------------
  const int lane = threadIdx.x & 63;
  float w1d[IN_F], w1b[IN_F];
#pragma unroll
  for (int c = 0; c < IN_F; ++c) {
    w1b[c] = W1[(IN_F + c) * HID + lane];
    w1d[c] = W1[c * HID + lane] - w1b[c];
  }
  const float b1v = b1[lane];
  int gw = __builtin_amdgcn_readfirstlane((((int)blockIdx.x - nSB) << 2) | (threadIdx.x >> 6));
  const int nwaves = 512 << 2;
  for (int n = gw; n < N; n += nwaves) {
    float p = b1v, q = 0.f;
#pragma unroll
    for (int c = 0; c < IN_F; ++c) {
      float xv = x[n * IN_F + c];
      p = fmaf(xv, w1d[c], p);
      q = fmaf(xv, w1b[c], q);
    }
    P[n * HID + lane] = p;
    Q[n * HID + lane] = (_Float16)q;
  }
}

// ---------------------------------------------------------------------------
// scan: per-bucket column exclusive scan over blocks, in place (hist -> offsets),
// plus per-bucket totals. One block per bucket, 256 threads, Hillis-Steele.
// ---------------------------------------------------------------------------
__global__ __launch_bounds__(256) void scan_kernel(
    unsigned* __restrict__ hist, unsigned* __restrict__ totals,
    int nblk, int NBKT)
{
  __shared__ unsigned s[256];
  const int b = blockIdx.x;
  const int tid = threadIdx.x;
  unsigned running = 0;
  const int nch = (nblk + 255) >> 8;
  for (int c = 0; c < nch; ++c) {
    const int idx = c * 256 + tid;
    unsigned v = (idx < nblk) ? hist[(size_t)idx * NBKT + b] : 0u;
    s[tid] = v;
    __syncthreads();
#pragma unroll
    for (int off = 1; off < 256; off <<= 1) {
      unsigned t = (tid >= off) ? s[tid - off] : 0u;
      __syncthreads();
      s[tid] += t;
      __syncthreads();
    }
    const unsigned incl = s[tid];
    const unsigned tot = s[255];
    if (idx < nblk) hist[(size_t)idx * NBKT + b] = running + (incl - v);
    running += tot;
    __syncthreads();
  }
  if (tid == 0) totals[b] = running;
}

// ---------------------------------------------------------------------------
// P1: coarse scatter. Re-reads edges, LDS-ranks within (block, bucket), writes
// payload + dlo to the bucket's dense region at base + blockOffset + rank.
// No global atomics (ovf append only, expected ~0).
// ---------------------------------------------------------------------------
__global__ __launch_bounds__(256) void p1_kernel(
    const int* __restrict__ ei, const float* __restrict__ ea,
    const unsigned* __restrict__ hist,
    uint2* __restrict__ cu, unsigned char* __restrict__ cdlo,
    uint4* __restrict__ ovf, int* __restrict__ ovf_cnt,
    int E, int NBKT)
{
  __shared__ unsigned h2[512];
  for (int i = threadIdx.x; i < NBKT; i += 256) h2[i] = 0;
  __syncthreads();
  const int base = blockIdx.x * 1024;
  int s[4], d[4]; bool v[4];
#pragma unroll
  for (int i = 0; i < 4; ++i) {
    int e = base + i * 256 + threadIdx.x;
    v[i] = e < E;
    int ec = v[i] ? e : 0;
    s[i] = ei[ec];
    d[i] = ei[(size_t)E + ec];
  }
  float a0[4], a1[4], a2[4];
#pragma unroll
  for (int i = 0; i < 4; ++i) {
    int ec = v[i] ? (base + i * 256 + threadIdx.x) : 0;
    a0[i] = ea[ec * 3 + 0]; a1[i] = ea[ec * 3 + 1]; a2[i] = ea[ec * 3 + 2];
  }
#pragma unroll
  for (int i = 0; i < 4; ++i) {
    if (!v[i]) continue;
    const int b = d[i] >> 7;
    const unsigned r = atomicAdd(&h2[b], 1u);                    // LDS atomic
    const unsigned pos = hist[(size_t)blockIdx.x * NBKT + b] + r; // block offset in bucket
    uint2 pay;
    pay.x = (unsigned)s[i] | ((unsigned)f2h_bits(a0[i]) << 16);  // src < 65536
    pay.y = (unsigned)f2h_bits(a1[i]) | ((unsigned)f2h_bits(a2[i]) << 16);
    if (pos < CAPB) {
      cu[(size_t)b * CAPB + pos] = pay;
      cdlo[(size_t)b * CAPB + pos] = (unsigned char)(d[i] & (DPB - 1));
    } else {
      int oi = atomicAdd(ovf_cnt, 1);
      if (oi < OVF_CAP) ovf[oi] = make_uint4(pay.x, pay.y, (unsigned)d[i], 0u);
    }
  }
}

// ---------------------------------------------------------------------------
// P2: per-bucket final scatter. LDS per-dst rank (128 counters) -> linear
// rec[d*RSL + rank]; writes cnt[d]. All writes dense / L2-local.
// ---------------------------------------------------------------------------
__global__ __launch_bounds__(512) void p2_kernel(
    const uint2* __restrict__ cu, const unsigned char* __restrict__ cdlo,
    const unsigned* __restrict__ totals,
    uint2* __restrict__ rec, int* __restrict__ cnt,
    uint4* __restrict__ ovf, int* __restrict__ ovf_cnt, int N)
{
  __shared__ int c[DPB];
  const int b = blockIdx.x;
  const int tid = threadIdx.x;
  if (tid < DPB) c[tid] = 0;
  __syncthreads();
  const int nE = (int)min(totals[b], (unsigned)CAPB);
  for (int i = tid; i < nE; i += 512) {
    const uint2 pay = cu[(size_t)b * CAPB + i];
    const int dlo = cdlo[(size_t)b * CAPB + i];
    const int r = atomicAdd(&c[dlo], 1);                          // LDS atomic
    const int d = b * DPB + dlo;
    if (r < RSL) rec[(size_t)d * RSL + r] = pay;
    else {
      int oi = atomicAdd(ovf_cnt, 1);
      if (oi < OVF_CAP) ovf[oi] = make_uint4(pay.x, pay.y, (unsigned)d, 0u);
    }
  }
  __syncthreads();
  if (tid < DPB) {
    const int d = b * DPB + tid;
    if (d < N) cnt[d] = c[tid];
  }
}

// ---------------------------------------------------------------------------
// bucket: R8 structure byte-for-byte except the prefetch — linear rec means
// m = cnt[d] (scalar load) and record i at rec[d*RSL+i]: the 8-counter prefix
// chain (~50 VALU/dst) is gone. VGPR stays <= 64 (R6/R9 rule).
// ---------------------------------------------------------------------------
__global__ __launch_bounds__(256) void bucket_kernel(
    const uint2* __restrict__ rec, const int* __restrict__ cnt,
    const float* __restrict__ W1, const float* __restrict__ W2,
    const float* __restrict__ P, const _Float16* __restrict__ Q,
    unsigned* __restrict__ agg, int N)
{
  __shared__ __align__(16) _Float16 hB[4][16][72];     // [wave][edge][ch]

  const int wave = threadIdx.x >> 6;
  const int lane = threadIdx.x & 63;
  const int quad = lane >> 4;
  const int eidx = lane & 15;
  // channel this lane stores in the final permuted row write
  const int mych = ((eidx >> 2) << 4) + (quad << 2) + (eidx & 3);

  // A-operand: W2^T fragments, fp16, loop-invariant (R2-verified).
  v8h a_frag[4][2];
#pragma unroll
  for (int t = 0; t < 4; ++t)
#pragma unroll
    for (int ks = 0; ks < 2; ++ks)
#pragma unroll
      for (int j = 0; j < 8; ++j)
        a_frag[t][ks][j] = (_Float16)W2[(ks * 32 + quad * 8 + j) * HID + t * 16 + eidx];

  const float w1c0 = W1[(2 * IN_F + 0) * HID + lane];
  const float w1c1 = W1[(2 * IN_F + 1) * HID + lane];
  const float w1c2 = W1[(2 * IN_F + 2) * HID + lane];

  const int gwave = __builtin_amdgcn_readfirstlane((blockIdx.x << 2) | wave);
  const int nw = gridDim.x << 2;

  int d = gwave;
  if (d >= N) return;   // waves are independent (no cross-wave LDS / syncthreads)

  int m; uint2 r0, r1; float pP;
  auto prefetch = [&](int dd) {
    m = min(cnt[dd], RSL);
    if (lane < m) r0 = rec[(size_t)dd * RSL + lane];
    if (m > 64) {       // wave-uniform rare branch (records 64..m)
      if (64 + lane < m) r1 = rec[(size_t)dd * RSL + 64 + lane];
    }
    pP = P[(size_t)dd * HID + lane];
  };

  prefetch(d);

  while (d < N) {
    const int dn = d + nw;
    const int m_cur = m;
    const float pvl = pP;
    uint2 ra = r0, rb = r1;   // active records for this dst

    if (m_cur > 0) {
      // ---- pad reg records: lanes >= m_cur get a copy of the last record ----
      {
        const int lm = m_cur - 1;
        unsigned rlx, rly;
        if (lm < 64) {
          rlx = (unsigned)__builtin_amdgcn_readlane((int)ra.x, lm);
          rly = (unsigned)__builtin_amdgcn_readlane((int)ra.y, lm);
        } else {
          rlx = (unsigned)__builtin_amdgcn_readlane((int)rb.x, lm & 63);
          rly = (unsigned)__builtin_amdgcn_readlane((int)rb.y, lm & 63);
        }
        if (lane >= m_cur)      { ra.x = rlx; ra.y = rly; }
        if (lane + 64 >= m_cur) { rb.x = rlx; rb.y = rly; }
      }

      // ---- tile-0 Q prefetch (uniform src -> saddr loads) ----
      float qv[16];
#pragma unroll
      for (int i = 0; i < 16; ++i) {
        unsigned sx = (unsigned)__builtin_amdgcn_readlane((int)ra.x, i) & 0xFFFFu;
        qv[i] = (float)Q[(size_t)sx * HID + lane];
      }

      // ---- prefetch next dst (cnt -> records -> P), lands under MFMA work ----
      if (dn < N) prefetch(dn);

      // ---- process current dst: 16-edge MFMA tiles (ntile <= 5) ----
      float maxv[4][4];
#pragma unroll
      for (int t = 0; t < 4; ++t)
#pragma unroll
        for (int r = 0; r < 4; ++r) maxv[t][r] = -INFINITY;

      const int ntile = (m_cur + 15) >> 4;
      for (int tb = 0; tb < ntile; ++tb) {
        const unsigned rsx = (tb < 4) ? ra.x : rb.x;
        const unsigned rsy = (tb < 4) ? ra.y : rb.y;
        const int b16 = (tb & 3) << 4;
#pragma unroll
        for (int i = 0; i < 16; ++i) {
          const unsigned rx = (unsigned)__builtin_amdgcn_readlane((int)rsx, b16 + i);
          const unsigned ry = (unsigned)__builtin_amdgcn_readlane((int)rsy, b16 + i);
          float pre = pvl + qv[i];
          pre = fmaf(h_bits2f((unsigned short)(rx >> 16)), w1c0, pre);
          pre = fmaf(h_bits2f((unsigned short)(ry & 0xFFFFu)), w1c1, pre);
          pre = fmaf(h_bits2f((unsigned short)(ry >> 16)), w1c2, pre);
          hB[wave][i][lane] = (_Float16)fmaxf(pre, 0.f);
        }
        __builtin_amdgcn_wave_barrier();

        const v8h bf0 = *(const v8h*)&hB[wave][eidx][quad * 8];
        const v8h bf1 = *(const v8h*)&hB[wave][eidx][32 + quad * 8];
        // refill qv <- tile tb+1 (issued between ds_read and MFMA)
        if (tb + 1 < ntile) {
          const unsigned rnx = (tb + 1 < 4) ? ra.x : rb.x;
          const int bn = ((tb + 1) & 3) << 4;
#pragma unroll
          for (int i = 0; i < 16; ++i) {
            unsigned sx = (unsigned)__builtin_amdgcn_readlane((int)rnx, bn + i) & 0xFFFFu;
            qv[i] = (float)Q[(size_t)sx * HID + lane];
          }
        }
#pragma unroll
        for (int t = 0; t < 4; ++t) {
          v4f acc = (v4f){0.f, 0.f, 0.f, 0.f};
          acc = __builtin_amdgcn_mfma_f32_16x16x32_f16(a_frag[t][0], bf0, acc, 0, 0, 0);
          acc = __builtin_amdgcn_mfma_f32_16x16x32_f16(a_frag[t][1], bf1, acc, 0, 0, 0);
#pragma unroll
          for (int r = 0; r < 4; ++r) maxv[t][r] = fmaxf(maxv[t][r], acc[r]);
        }
        __builtin_amdgcn_wave_barrier();
      }

      // ---- butterfly max over the 16 edge-columns, direct permuted row store ----
#pragma unroll
      for (int t = 0; t < 4; ++t)
#pragma unroll
        for (int r = 0; r < 4; ++r) {
          float v = maxv[t][r];
          v = fmaxf(v, __shfl_xor(v, 1, 64));
          v = fmaxf(v, __shfl_xor(v, 2, 64));
          v = fmaxf(v, __shfl_xor(v, 4, 64));
          v = fmaxf(v, __shfl_xor(v, 8, 64));
          maxv[t][r] = v;
        }
      float val = maxv[0][0];
#pragma unroll
      for (int t = 0; t < 4; ++t)
#pragma unroll
        for (int r = 0; r < 4; ++r)
          val = (eidx == t * 4 + r) ? maxv[t][r] : val;
      agg[(size_t)d * HID + mych] = ordenc(val);   // permutation within one 256B row
    } else {
      // empty dst; still run the next-dst prefetch to keep the pipeline primed
      if (dn < N) prefetch(dn);
      agg[(size_t)d * HID + lane] = ORD_NEG_INF;
    }
    d = dn;
  }
}

// Fallback for overflow (expected ~0). Payload-form records {src|a0, a1|a2, d}.
// Same fp16-attr math as bucket, fp32 accumulation; atomicMax after bucket.
__global__ __launch_bounds__(256) void overflow_kernel(
    const uint4* __restrict__ ovf, const int* __restrict__ ovf_cnt,
    const float* __restrict__ W1, const float* __restrict__ W2,
    const float* __restrict__ P, const _Float16* __restrict__ Q,
    unsigned* __restrict__ agg)
{
  __shared__ float hsh[4][HID];
  const int wave = threadIdx.x >> 6;
  const int lane = threadIdx.x & 63;

  int M = *ovf_cnt;
  if (M > OVF_CAP) M = OVF_CAP;
  if (M == 0) return;

  float w2r[HID];
#pragma unroll
  for (int j = 0; j < HID; ++j) w2r[j] = W2[j * HID + lane];
  const float w1c0 = W1[(2 * IN_F + 0) * HID + lane];
  const float w1c1 = W1[(2 * IN_F + 1) * HID + lane];
  const float w1c2 = W1[(2 * IN_F + 2) * HID + lane];

  const int gwave = __builtin_amdgcn_readfirstlane((blockIdx.x << 2) | wave);
  const int nw = gridDim.x << 2;
  for (int k = gwave; k < M; k += nw) {
    const uint4 o = ovf[k];
    const int s = (int)(o.x & 0xFFFFu);
    const int d = (int)o.z;
    float pre = P[(size_t)d * HID + lane] + (float)Q[(size_t)s * HID + lane];
    pre = fmaf(h_bits2f((unsigned short)(o.x >> 16)), w1c0, pre);
    pre = fmaf(h_bits2f((unsigned short)(o.y & 0xFFFFu)), w1c1, pre);
    pre = fmaf(h_bits2f((unsigned short)(o.y >> 16)), w1c2, pre);
    hsh[wave][lane] = fmaxf(pre, 0.f);
    __builtin_amdgcn_wave_barrier();
    float mv = 0.f;
#pragma unroll
    for (int j = 0; j < HID; ++j) mv = fmaf(hsh[wave][j], w2r[j], mv);
    atomicMax(&agg[(size_t)d * HID + lane], ordenc(mv));
    __builtin_amdgcn_wave_barrier();
  }
}

// 16 nodes per block: decode agg (empty -> 0, else +b2), out = sigmoid(agg @ Wo + bo)
__global__ __launch_bounds__(256) void out_kernel(
    const unsigned* __restrict__ agg,
    const float* __restrict__ b2,
    const float* __restrict__ Wo, const float* __restrict__ bo,
    float* __restrict__ out, int N)
{
  __shared__ float Wos[HID * OUTF];
  __shared__ float bos[OUTF];
  __shared__ float b2s[HID];
  __shared__ float aggs[16][HID + 1];

  for (int i = threadIdx.x; i < HID * OUTF; i += 256) Wos[i] = Wo[i];
  if (threadIdx.x < OUTF) bos[threadIdx.x] = bo[threadIdx.x];
  if (threadIdx.x < HID) b2s[threadIdx.x] = b2[threadIdx.x];
  __syncthreads();

  const int nodeBase = blockIdx.x * 16;
  {
    int ln = threadIdx.x >> 4;
    int k0 = (threadIdx.x & 15) * 4;
    int n = nodeBase + ln;
    if (n < N) {
      const uint4 u = *(const uint4*)&agg[(size_t)n * HID + k0];
      aggs[ln][k0 + 0] = (u.x == ORD_NEG_INF) ? 0.f : orddec(u.x) + b2s[k0 + 0];
      aggs[ln][k0 + 1] = (u.y == ORD_NEG_INF) ? 0.f : orddec(u.y) + b2s[k0 + 1];
      aggs[ln][k0 + 2] = (u.z == ORD_NEG_INF) ? 0.f : orddec(u.z) + b2s[k0 + 2];
      aggs[ln][k0 + 3] = (u.w == ORD_NEG_INF) ? 0.f : orddec(u.w) + b2s[k0 + 3];
    }
  }
  __syncthreads();
  {
    int ln = threadIdx.x >> 4;
    int o = threadIdx.x & 15;
    int n = nodeBase + ln;
    if (n < N) {
      float acc = bos[o];
#pragma unroll
      for (int k = 0; k < HID; ++k) acc = fmaf(aggs[ln][k], Wos[k * OUTF + o], acc);
      out[n * OUTF + o] = 1.f / (1.f + __expf(-acc));
    }
  }
}

extern "C" void kernel_launch(void* const* d_in, const int* in_sizes, int n_in,
                              void* d_out, int out_size, void* d_ws, size_t ws_size,
                              hipStream_t stream) {
  const float* x  = (const float*)d_in[0];
  const int*   ei = (const int*)d_in[1];
  const float* ea = (const float*)d_in[2];
  const float* W1 = (const float*)d_in[3];
  const float* b1 = (const float*)d_in[4];
  const float* W2 = (const float*)d_in[5];
  const float* b2 = (const float*)d_in[6];
  const float* Wo = (const float*)d_in[7];
  const float* bo = (const float*)d_in[8];
  float* out = (float*)d_out;

  const int N = in_sizes[0] / IN_F;    // 50000
  const int E = in_sizes[1] / 2;       // 1600000
  const int NBKT = (N + DPB - 1) / DPB;   // 391
  const int nSB  = (E + 1023) / 1024;     // 1563

  // ws layout (16B-aligned regions), ~86 MB total:
  // P(12.8M) | Q fp16(6.4M) | agg(12.8M) | rec N*RSL*8(32M) | cu NBKT*CAPB*8(16M)
  // | hist nSB*NBKT*4(2.45M) | totals | cnt(0.2M) | cdlo NBKT*CAPB(2M) | ovf_cnt | ovf(1M)
  char* w = (char*)d_ws;
  auto align16 = [](size_t v) { return (v + 15) & ~(size_t)15; };
  float*     Pp   = (float*)w;       w += align16((size_t)N * HID * 4);
  _Float16*  Qp   = (_Float16*)w;    w += align16((size_t)N * HID * 2);
  unsigned*  agg  = (unsigned*)w;    w += align16((size_t)N * HID * 4);
  uint2*     rec  = (uint2*)w;       w += align16((size_t)N * RSL * 8);
  uint2*     cu   = (uint2*)w;       w += align16((size_t)NBKT * CAPB * 8);
  unsigned*  hist = (unsigned*)w;    w += align16((size_t)nSB * NBKT * 4);
  unsigned*  tot  = (unsigned*)w;    w += align16((size_t)NBKT * 4);
  int*       cnt  = (int*)w;         w += align16((size_t)N * 4);
  unsigned char* cdlo = (unsigned char*)w; w += align16((size_t)NBKT * CAPB);
  int*   ovf_cnt  = (int*)w;         w += 16;
  uint4*     ovf  = (uint4*)w;

  hipMemsetAsync(ovf_cnt, 0, 16, stream);

  p0_kernel<<<nSB + 512, 256, 0, stream>>>(ei, x, W1, b1, Pp, Qp, hist, E, N, nSB, NBKT);
  scan_kernel<<<NBKT, 256, 0, stream>>>(hist, tot, nSB, NBKT);
  p1_kernel<<<nSB, 256, 0, stream>>>(ei, ea, hist, cu, cdlo, ovf, ovf_cnt, E, NBKT);
  p2_kernel<<<NBKT, 512, 0, stream>>>(cu, cdlo, tot, rec, cnt, ovf, ovf_cnt, N);
  bucket_kernel<<<4096, 256, 0, stream>>>(rec, cnt, W1, W2, Pp, Qp, agg, N);
  overflow_kernel<<<256, 256, 0, stream>>>(ovf, ovf_cnt, W1, W2, Pp, Qp, agg);
  out_kernel<<<(N + 15) / 16, 256, 0, stream>>>(agg, b2, Wo, bo, out, N);
}